// Round 1
// baseline (945.124 us; speedup 1.0000x reference)
//
#include <hip/hip_runtime.h>
#include <math.h>

// Problem constants (from reference)
#define N_TOKENS  16384
#define D_MODEL   4096
#define N_EXPERTS 64
#define CAPACITY  308          // ceil(1.2 * 16384 / 64)
#define BUCKET_CAP 1024        // counts ~ Binom(32768, 1/64): mu=512, sigma=22 -> +23 sigma

// GEMM tiling
#define TOK_PER_BLK 32
#define KC 64
#define LDPAD 68               // row stride in floats, 16B aligned, 2-way max bank aliasing

// ws layout (bytes): [0,256) int cnt[64]; [256,512) float imp[64]; [512,...) buckets
//
// Output layout (all float32, flat):
//   [0, 32768)        topk_ids   (as float)
//   [32768, 65536)    topk_gates
//   [65536]           aux_loss
//   [65537, 98305)    mask (0.0 / 1.0)

__global__ __launch_bounds__(256) void router_kernel(
    const float* __restrict__ x, const float* __restrict__ W,
    const float* __restrict__ b,
    float* __restrict__ out_ids, float* __restrict__ out_gates,
    int* __restrict__ cnt, float* __restrict__ imp,
    float2* __restrict__ bucket, int bucket_cap)
{
    __shared__ float xs[TOK_PER_BLK][LDPAD];            // 8704 B
    __shared__ float wsh[N_EXPERTS][LDPAD];             // 17408 B
    __shared__ float logits_s[TOK_PER_BLK][N_EXPERTS + 1]; // 8320 B
    __shared__ float imp_s[4][N_EXPERTS];               // 1024 B

    const int tid = threadIdx.x;
    const int tx = tid & 15;        // token group: tokens tx, tx+16
    const int ty = tid >> 4;        // expert group: experts 4ty..4ty+3
    const int tbase = blockIdx.x * TOK_PER_BLK;

    float acc[2][4] = {{0.f,0.f,0.f,0.f},{0.f,0.f,0.f,0.f}};

    for (int kc = 0; kc < D_MODEL; kc += KC) {
        // ---- stage x tile: 32 tokens x 64 k (coalesced float4) ----
        {
            int q = tid;
            #pragma unroll
            for (int r = 0; r < 2; r++) {
                int t  = q >> 4;            // [0,32)
                int kq = (q & 15) << 2;     // [0,64) step 4
                float4 v = *(const float4*)&x[(size_t)(tbase + t) * D_MODEL + kc + kq];
                *(float4*)&xs[t][kq] = v;
                q += 256;
            }
            int p = tid;
            #pragma unroll
            for (int r = 0; r < 4; r++) {
                int e  = p >> 4;            // [0,64)
                int kq = (p & 15) << 2;
                float4 v = *(const float4*)&W[(size_t)e * D_MODEL + kc + kq];
                *(float4*)&wsh[e][kq] = v;
                p += 256;
            }
        }
        __syncthreads();

        // ---- compute: 2 tokens x 4 experts per thread, float4 along k ----
        #pragma unroll
        for (int k4 = 0; k4 < KC; k4 += 4) {
            float4 xa = *(const float4*)&xs[tx][k4];
            float4 xb = *(const float4*)&xs[tx + 16][k4];
            #pragma unroll
            for (int i = 0; i < 4; i++) {
                float4 wv = *(const float4*)&wsh[(ty << 2) + i][k4];
                acc[0][i] = fmaf(xa.x, wv.x, acc[0][i]);
                acc[0][i] = fmaf(xa.y, wv.y, acc[0][i]);
                acc[0][i] = fmaf(xa.z, wv.z, acc[0][i]);
                acc[0][i] = fmaf(xa.w, wv.w, acc[0][i]);
                acc[1][i] = fmaf(xb.x, wv.x, acc[1][i]);
                acc[1][i] = fmaf(xb.y, wv.y, acc[1][i]);
                acc[1][i] = fmaf(xb.z, wv.z, acc[1][i]);
                acc[1][i] = fmaf(xb.w, wv.w, acc[1][i]);
            }
        }
        __syncthreads();
    }

    // ---- epilogue: add bias, park logits in LDS ----
    #pragma unroll
    for (int i = 0; i < 4; i++) {
        int e = (ty << 2) + i;
        float be = b[e];
        logits_s[tx][e]      = acc[0][i] + be;
        logits_s[tx + 16][e] = acc[1][i] + be;
    }
    __syncthreads();

    // ---- softmax + top-2 per token: lane = expert, wave handles 8 tokens ----
    const int wave = tid >> 6;
    const int lane = tid & 63;
    float impacc = 0.f;

    for (int j = 0; j < 8; j++) {
        int t = wave * 8 + j;
        float v = logits_s[t][lane];

        float m = v;
        #pragma unroll
        for (int s = 32; s > 0; s >>= 1) m = fmaxf(m, __shfl_xor(m, s));
        float p = expf(v - m);
        float sum = p;
        #pragma unroll
        for (int s = 32; s > 0; s >>= 1) sum += __shfl_xor(sum, s);
        float prob = p / sum;
        impacc += prob;

        // argmax #1 (lowest index wins ties -> matches jax.lax.top_k)
        float bp = prob; int bi = lane;
        #pragma unroll
        for (int s = 32; s > 0; s >>= 1) {
            float op = __shfl_xor(bp, s); int oi = __shfl_xor(bi, s);
            if (op > bp || (op == bp && oi < bi)) { bp = op; bi = oi; }
        }
        // argmax #2 (exclude winner; probs >= 0 so -1 acts as -inf)
        float p2 = (lane == bi) ? -1.f : prob;
        float bp2 = p2; int bi2 = lane;
        #pragma unroll
        for (int s = 32; s > 0; s >>= 1) {
            float op = __shfl_xor(bp2, s); int oi = __shfl_xor(bi2, s);
            if (op > bp2 || (op == bp2 && oi < bi2)) { bp2 = op; bi2 = oi; }
        }

        if (lane == 0) {
            int tok = tbase + t;
            out_ids[tok * 2]     = (float)bi;
            out_ids[tok * 2 + 1] = (float)bi2;
            out_gates[tok * 2]     = bp;
            out_gates[tok * 2 + 1] = bp2;
            int pos0 = atomicAdd(&cnt[bi], 1);
            if (pos0 < bucket_cap)
                bucket[bi * bucket_cap + pos0] = make_float2(bp, __int_as_float(tok * 2));
            int pos1 = atomicAdd(&cnt[bi2], 1);
            if (pos1 < bucket_cap)
                bucket[bi2 * bucket_cap + pos1] = make_float2(bp2, __int_as_float(tok * 2 + 1));
        }
    }

    // ---- importance: 4-wave LDS combine, then 64 atomics per block ----
    imp_s[wave][lane] = impacc;
    __syncthreads();
    if (wave == 0) {
        float s = imp_s[0][lane] + imp_s[1][lane] + imp_s[2][lane] + imp_s[3][lane];
        atomicAdd(&imp[lane], s);
    }
}

// One block per expert: exact lexsort rank via O(n^2) comparison in LDS.
// keep iff #{j : g_j > g_i || (g_j == g_i && idx_j < idx_i)} < CAPACITY
__global__ __launch_bounds__(256) void capacity_kernel(
    const int* __restrict__ cnt, const float2* __restrict__ bucket,
    float* __restrict__ out_mask, int bucket_cap)
{
    __shared__ float g_s[BUCKET_CAP];
    __shared__ int   i_s[BUCKET_CAP];
    const int e = blockIdx.x;
    int n = cnt[e];
    if (n > bucket_cap) n = bucket_cap;

    for (int i = threadIdx.x; i < n; i += 256) {
        float2 r = bucket[e * bucket_cap + i];
        g_s[i] = r.x;
        i_s[i] = __float_as_int(r.y);
    }
    __syncthreads();

    for (int i = threadIdx.x; i < n; i += 256) {
        float gi = g_s[i]; int ii = i_s[i];
        int rank = 0;
        for (int j = 0; j < n; j++) {
            float gj = g_s[j]; int ij = i_s[j];
            rank += (gj > gi || (gj == gi && ij < ii)) ? 1 : 0;
        }
        out_mask[ii] = (rank < CAPACITY) ? 1.f : 0.f;
    }
}

__global__ void aux_kernel(const int* __restrict__ cnt,
                           const float* __restrict__ imp,
                           float* __restrict__ out_aux)
{
    int lane = threadIdx.x;  // 64 threads = 1 wave
    float load = (float)min(cnt[lane], CAPACITY);
    float v = (float)N_EXPERTS * (imp[lane] / (float)N_TOKENS) * (load / (float)N_TOKENS);
    #pragma unroll
    for (int s = 32; s > 0; s >>= 1) v += __shfl_xor(v, s);
    if (lane == 0) out_aux[0] = v;
}

extern "C" void kernel_launch(void* const* d_in, const int* in_sizes, int n_in,
                              void* d_out, int out_size, void* d_ws, size_t ws_size,
                              hipStream_t stream) {
    const float* x = (const float*)d_in[0];
    const float* W = (const float*)d_in[1];
    const float* b = (const float*)d_in[2];
    // d_in[3] = training flag (always 0: eval path)

    float* out       = (float*)d_out;
    float* out_ids   = out;
    float* out_gates = out + 32768;
    float* out_aux   = out + 65536;
    float* out_mask  = out + 65537;

    int*    cnt    = (int*)d_ws;
    float*  imp    = (float*)((char*)d_ws + 256);
    float2* bucket = (float2*)((char*)d_ws + 512);

    // Size bucket to the workspace we actually have (expected count/expert ~512).
    int bucket_cap = (int)((ws_size > 512 ? (ws_size - 512) : 0) / (N_EXPERTS * sizeof(float2)));
    if (bucket_cap > BUCKET_CAP) bucket_cap = BUCKET_CAP;

    hipMemsetAsync(d_ws, 0, 512, stream);  // zero cnt + imp

    router_kernel<<<N_TOKENS / TOK_PER_BLK, 256, 0, stream>>>(
        x, W, b, out_ids, out_gates, cnt, imp, bucket, bucket_cap);
    capacity_kernel<<<N_EXPERTS, 256, 0, stream>>>(cnt, bucket, out_mask, bucket_cap);
    aux_kernel<<<1, 64, 0, stream>>>(cnt, imp, out_aux);
}